// Round 3
// baseline (8102.891 us; speedup 1.0000x reference)
//
#include <hip/hip_runtime.h>
#include <math.h>
#include <stdint.h>

// ---------------- constants ----------------
#define T_STEPS 191      // 200 - 9
#define NB1 31
#define YS 13            // y feature stride

// ---------------- MFMA types/helpers ----------------
typedef short bf8 __attribute__((ext_vector_type(8)));    // 8 bf16 (4 VGPRs)
typedef float f16x __attribute__((ext_vector_type(16)));  // 32x32 accumulator

#define MFMA32 __builtin_amdgcn_mfma_f32_32x32x16_bf16

__device__ __forceinline__ float sigmoid_(float x) { return 1.f / (1.f + expf(-x)); }

__device__ __forceinline__ unsigned bf16b(float x){        // RNE fp32->bf16 bits
  unsigned u = __float_as_uint(x);
  return (u + 0x7fffu + ((u>>16)&1u)) >> 16;
}
__device__ __forceinline__ float bf16f(unsigned b){ return __uint_as_float(b<<16); }

__device__ __forceinline__ bf8 ldfrag(const unsigned short* p, int slot){
  uint4 u = *reinterpret_cast<const uint4*>(p + slot*8);   // ds_read_b128
  return __builtin_bit_cast(bf8, u);
}
__device__ __forceinline__ bf8 ldg4(const unsigned* p){
  uint4 u = *reinterpret_cast<const uint4*>(p);            // 16B load
  return __builtin_bit_cast(bf8, u);
}
// transposed gather: 8 bf16 at stride 8 ushorts (consecutive m in A-layout)
__device__ __forceinline__ bf8 gather8(const unsigned short* fr, int base){
  unsigned w0 = (unsigned)fr[base]    | ((unsigned)fr[base+8]<<16);
  unsigned w1 = (unsigned)fr[base+16] | ((unsigned)fr[base+24]<<16);
  unsigned w2 = (unsigned)fr[base+32] | ((unsigned)fr[base+40]<<16);
  unsigned w3 = (unsigned)fr[base+48] | ((unsigned)fr[base+56]<<16);
  uint4 u; u.x=w0; u.y=w1; u.z=w2; u.w=w3;
  return __builtin_bit_cast(bf8, u);
}
__device__ __forceinline__ f16x zf16(){
  f16x v;
#pragma unroll
  for (int q=0;q<16;++q) v[q]=0.f;
  return v;
}
// A-layout slot for element (m, k):  ((k>>4)*64 + m + ((k>>3)&1)*32)*8 + (k&7)
__device__ __forceinline__ int aslot(int m, int k){
  return ((k>>4)*64 + m + ((k>>3)&1)*32)*8 + (k&7);
}

// ---------------- tiled fp32 GEMM: C = act(A @ B + bias) (unchanged, proven) ----------------
template <bool GATHER, bool RELU>
__global__ __launch_bounds__(256) void gemm_tiled(
    const float* __restrict__ A, const float* __restrict__ B,
    const float* __restrict__ bias, float* __restrict__ C,
    int M, int N, int K)
{
    __shared__ float As[16][65];
    __shared__ float Bs[16][65];
    const int tid = threadIdx.x;
    const int tm = tid >> 4, tn = tid & 15;
    const int rowBase = blockIdx.y * 64;
    const int colBase = blockIdx.x * 64;
    float acc[4][4] = {};
    for (int kt = 0; kt < K; kt += 16) {
        #pragma unroll
        for (int l = 0; l < 4; ++l) {
            const int idx = tid + l * 256;
            const int kk = idx & 15, rr = idx >> 4;
            const int row = rowBase + rr;
            float v = 0.f;
            if (row < M) {
                if (GATHER) {
                    const int t = row / 30, i = row - t * 30;
                    const int k = kt + kk;
                    const int src = (k < 256) ? ((t * NB1 + i + 1) * 256 + k)
                                              : (t * NB1 * 256 + (k - 256));
                    v = A[src];
                } else {
                    v = A[(size_t)row * K + kt + kk];
                }
            }
            As[kk][rr] = v;
            const int nn = idx & 63, k2 = idx >> 6;
            Bs[k2][nn] = B[(size_t)(kt + k2) * N + colBase + nn];
        }
        __syncthreads();
        #pragma unroll
        for (int kk = 0; kk < 16; ++kk) {
            float a[4], b[4];
            #pragma unroll
            for (int i = 0; i < 4; ++i) a[i] = As[kk][tm * 4 + i];
            #pragma unroll
            for (int j = 0; j < 4; ++j) b[j] = Bs[kk][tn * 4 + j];
            #pragma unroll
            for (int i = 0; i < 4; ++i)
                #pragma unroll
                for (int j = 0; j < 4; ++j)
                    acc[i][j] = fmaf(a[i], b[j], acc[i][j]);
        }
        __syncthreads();
    }
    #pragma unroll
    for (int i = 0; i < 4; ++i) {
        const int row = rowBase + tm * 4 + i;
        if (row < M) {
            #pragma unroll
            for (int j = 0; j < 4; ++j) {
                const int col = colBase + tn * 4 + j;
                float v = acc[i][j] + bias[col];
                if (RELU) v = fmaxf(v, 0.f);
                C[(size_t)row * N + col] = v;
            }
        }
    }
}

// ---------------- prep: gate weights -> B-fragment layout, cols permuted ----------------
// wpg index = ((nt*16 + kb)*64 + lane)*4 + j ; nt = 3*g + gate (g = 32-dim group)
__global__ __launch_bounds__(256) void prep_wg(const float* __restrict__ Whg,
                                               unsigned* __restrict__ wpg)
{
    const int idx = blockIdx.x * 256 + threadIdx.x;     // < 24*16*64*4 = 98304
    const int j  = idx & 3;
    const int l  = (idx >> 2) & 63;
    const int kb = (idx >> 8) & 15;
    const int nt = idx >> 12;                            // 0..23
    const int g = nt / 3, gate = nt - g * 3;
    const int col = gate * 256 + g * 32 + (l & 31);
    const int k2 = kb * 8 + ((l >> 5) << 2) + j;
    const unsigned lo = bf16b(Whg[(size_t)(2 * k2) * 768 + col]);
    const unsigned hi = bf16b(Whg[(size_t)(2 * k2 + 1) * 768 + col]);
    wpg[idx] = lo | (hi << 16);
}

// heads B (K=288: hn 0..255 -> Wpbox rows 0..255 / Wout; hc 256..287 -> rows 512..543)
__global__ __launch_bounds__(256) void prep_hd(const float* __restrict__ Wpbox,
                                               const float* __restrict__ Wout,
                                               unsigned* __restrict__ hdh,
                                               unsigned* __restrict__ hdl)
{
    const int idx = blockIdx.x * 256 + threadIdx.x;     // < 2*18*64*4 = 9216
    if (idx >= 9216) return;
    const int j = idx & 3;
    const int l = (idx >> 2) & 63;
    const int kbnt = idx >> 8;                           // 0..35
    const int kb = kbnt % 18, nt = kbnt / 18;
    const int d = nt * 32 + (l & 31);
    const int k0 = kb * 16 + ((l >> 5) << 3) + 2 * j;
    float v0 = 0.f, v1 = 0.f;
    if (d < 37) {
        const int r0 = (k0 < 256) ? k0 : 512 + (k0 - 256);
        const int r1 = (k0 + 1 < 256) ? (k0 + 1) : 512 + (k0 + 1 - 256);
        v0 = (d < 36) ? Wpbox[(size_t)r0 * 36 + d] : Wout[r0];
        v1 = (d < 36) ? Wpbox[(size_t)r1 * 36 + d] : Wout[r1];
    }
    const unsigned h0 = bf16b(v0), h1 = bf16b(v1);
    const unsigned l0 = bf16b(v0 - bf16f(h0)), l1 = bf16b(v1 - bf16f(h1));
    hdh[idx] = h0 | (h1 << 16);
    hdl[idx] = l0 | (l1 << 16);
}

// hc gate weights (nt = gate): index = ((nt*2 + kb)*64 + lane)*4 + j
__global__ __launch_bounds__(256) void prep_hcw(const float* __restrict__ Whc,
                                                unsigned* __restrict__ hch,
                                                unsigned* __restrict__ hcl)
{
    const int idx = blockIdx.x * 256 + threadIdx.x;     // < 3*2*64*4 = 1536
    if (idx >= 1536) return;
    const int j = idx & 3;
    const int l = (idx >> 2) & 63;
    const int kb = (idx >> 8) & 1;
    const int nt = idx >> 9;                             // 0..2
    const int col = nt * 32 + (l & 31);
    const int k0 = kb * 16 + ((l >> 5) << 3) + 2 * j;
    const float v0 = Whc[k0 * 96 + col];
    const float v1 = Whc[(k0 + 1) * 96 + col];
    const unsigned h0 = bf16b(v0), h1 = bf16b(v1);
    const unsigned l0 = bf16b(v0 - bf16f(h0)), l1 = bf16b(v1 - bf16f(h1));
    hch[idx] = h0 | (h1 << 16);
    hcl[idx] = l0 | (l1 << 16);
}

// combined biases: r/z gates get bx+bh (additive), n gate keeps bx only
__global__ void prep_bias(const float* __restrict__ bxg, const float* __restrict__ bhg,
                          const float* __restrict__ bxc, const float* __restrict__ bhc,
                          float* __restrict__ biasg, float* __restrict__ biasc)
{
    const int t = threadIdx.x;
    if (t < 768) biasg[t] = bxg[t] + (t < 512 ? bhg[t] : 0.f);
    if (t < 96)  biasc[t] = bxc[t] + (t < 64 ? bhc[t] : 0.f);
}

// ---------------- per-(t,obj) small precompute (unchanged, proven) ----------------
__global__ __launch_bounds__(256) void precomp_kernel(
    const float* __restrict__ y,
    const float* __restrict__ Wbb, const float* __restrict__ bbb,
    const float* __restrict__ Wdd, const float* __restrict__ bdd,
    const float* __restrict__ Wproj, const float* __restrict__ bproj,
    const float* __restrict__ Wxc, const float* __restrict__ biasc,
    const float* __restrict__ Wpbox, const float* __restrict__ bpbox,
    const float* __restrict__ Wout, const float* __restrict__ bout,
    float* __restrict__ gxc, float* __restrict__ pbox_b, float* __restrict__ logit_b)
{
    const int m = blockIdx.x;
    const int tid = threadIdx.x;
    __shared__ float bf[256], df[256], xcs[32], yl[16];
    if (tid < YS) yl[tid] = y[m * YS + tid];
    __syncthreads();
    const float invnorm[4] = {1.f/1920.f, 1.f/1200.f, 1.f/1920.f, 1.f/1200.f};
    {
        float s = bbb[tid];
        s = fmaf(yl[1] * invnorm[0], Wbb[0 * 256 + tid], s);
        s = fmaf(yl[2] * invnorm[1], Wbb[1 * 256 + tid], s);
        s = fmaf(yl[3] * invnorm[2], Wbb[2 * 256 + tid], s);
        s = fmaf(yl[4] * invnorm[3], Wbb[3 * 256 + tid], s);
        s = fmaf(yl[6],              Wbb[4 * 256 + tid], s);
        bf[tid] = fmaxf(s, 0.f);
    }
    {
        float s = bdd[tid];
        #pragma unroll
        for (int k = 0; k < 6; ++k) s = fmaf(yl[7 + k], Wdd[k * 256 + tid], s);
        df[tid] = fmaxf(s, 0.f);
    }
    __syncthreads();
    {
        const int c = tid >> 3, p = tid & 7;
        float s = 0.f;
        for (int k = p; k < 256; k += 8) s = fmaf(df[k], Wproj[k * 32 + c], s);
        s += __shfl_xor(s, 1); s += __shfl_xor(s, 2); s += __shfl_xor(s, 4);
        if (p == 0) xcs[c] = s + bproj[c];
    }
    __syncthreads();
    if (tid < 96) {
        float s = biasc[tid];
        #pragma unroll
        for (int k = 0; k < 32; ++k) s = fmaf(xcs[k], Wxc[k * 96 + tid], s);
        gxc[m * 96 + tid] = s;
    }
    {
        const int d = tid >> 2, p = tid & 3;
        if (d < 37) {
            float s = 0.f;
            if (d < 36) {
                for (int k = p; k < 256; k += 4) s = fmaf(bf[k], Wpbox[(256 + k) * 36 + d], s);
            } else {
                for (int k = p; k < 256; k += 4) s = fmaf(bf[k], Wout[256 + k], s);
            }
            s += __shfl_xor(s, 1); s += __shfl_xor(s, 2);
            if (p == 0) {
                if (d < 36) pbox_b[m * 36 + d] = s + bpbox[d];
                else        logit_b[m] = s + bout[0];
            }
        }
    }
}

// ---------------- single-block fully-redundant MFMA recurrence ----------------
// 1 block x 512 threads (8 waves). Wave w owns dim group [32w, 32w+32).
// Full gate/score/attn computed locally each step -> ZERO inter-block sync.
// Weights stream from L2 (wpg 384KB stays warm); combine fully in-register.
__global__ __launch_bounds__(512, 1) void seq1(
    const float* __restrict__ y,
    const float* __restrict__ gxg,      // 5730 x 768 (bias-combined x-side)
    const float* __restrict__ gxc,      // 5730 x 96
    const float* __restrict__ pbox_b,   // 5730 x 36
    const float* __restrict__ logit_b,  // 5730
    const unsigned* __restrict__ wpg,   // gate B frags (bf16 pairs), 24*4096
    const unsigned* __restrict__ hdh, const unsigned* __restrict__ hdl, // heads B hi/lo
    const unsigned* __restrict__ hch, const unsigned* __restrict__ hcl, // hc B hi/lo
    const float* __restrict__ bhg,      // 768 (n-part used)
    const float* __restrict__ bhc,      // 96 (n-part used)
    float* __restrict__ out)
{
    const int tid = threadIdx.x;
    const int lane = tid & 63, wid = tid >> 6;
    const int half = lane >> 5, ln31 = lane & 31;
    const int dd = wid * 32 + ln31;          // this lane's h-dim

    __shared__ __align__(16) unsigned short hA_hi[8192], hA_lo[8192]; // h / h2 frags
    __shared__ __align__(16) unsigned short cf_hi[1024],  cf_lo[1024];  // hc / hc2 frags
    __shared__ __align__(16) unsigned short wf_hi[1024],  wf_lo[1024];  // attn w frags
    __shared__ __align__(16) unsigned short cwf_hi[1024], cwf_lo[1024]; // hc attn w frags
    __shared__ float exch[4096];   // hc-gate outs (P1) / scores (P3)
    __shared__ float pbl[1280];    // head outputs [obj][40]
    __shared__ float actf[32], red[16];

    for (int i = tid; i < 8192; i += 512){ hA_hi[i] = 0; hA_lo[i] = 0; }
    for (int i = tid; i < 1024; i += 512){
        cf_hi[i]=0; cf_lo[i]=0; wf_hi[i]=0; wf_lo[i]=0; cwf_hi[i]=0; cwf_lo[i]=0;
    }
    const float bnd = bhg[512 + dd];
    const float bnc = bhc[64 + ln31];

    float hreg[16], hcreg[16];
#pragma unroll
    for (int q = 0; q < 16; ++q){ hreg[q] = 0.f; hcreg[q] = 0.f; }
    float bacc = 0.f, oacc = 0.f;

    // fixed per-thread loss-cell mapping (waves 2-7, 3 cells each over 30x37)
    int lobj[3], ldc[3]; bool lval[3];
#pragma unroll
    for (int r3 = 0; r3 < 3; ++r3){
        const int c = (tid - 128) + 384 * r3;
        lval[r3] = (wid >= 2) && (c >= 0) && (c < 1110);
        const int cc2 = lval[r3] ? c : 0;
        lobj[r3] = cc2 / 37; ldc[r3] = cc2 - lobj[r3] * 37;
    }
    __syncthreads();

    for (int t = 0; t < T_STEPS; ++t){
        const int m0 = t * 30;

        // ---- P0: act flags + x-side gate prefetch + loss operand prefetch ----
        if (tid < 32) actf[tid] = (tid < 30 && y[(size_t)(m0 + tid) * YS] != 0.f) ? 1.f : 0.f;
        float gr[16], gz[16], gn[16];
#pragma unroll
        for (int q = 0; q < 16; ++q){
            const int obj = (q&3) + ((q>>2)<<3) + (half<<2);
            if (obj < 30){
                const float* gp = gxg + (size_t)(m0 + obj) * 768 + dd;
                gr[q] = gp[0]; gz[q] = gp[256]; gn[q] = gp[512];
            } else { gr[q] = 0.f; gz[q] = 0.f; gn[q] = 0.f; }
        }
        float pfu[3], ppb[3]; float ptg = 0.f;
#pragma unroll
        for (int r3 = 0; r3 < 3; ++r3){
            pfu[r3] = 0.f; ppb[r3] = 0.f;
            if (lval[r3]){
                const int obj = lobj[r3], d = ldc[r3];
                const int m = m0 + obj;
                if (d < 36){
                    const int s4 = d >> 2, cc = d & 3;
                    const float fn = (cc & 1) ? (1.f/1200.f) : (1.f/1920.f);
                    pfu[r3] = y[(size_t)((t + 1 + s4)*30 + obj)*YS + 1 + cc] * fn;
                    ppb[r3] = pbox_b[(size_t)m*36 + d];
                } else {
                    ppb[r3] = logit_b[m];
                    ptg = y[(size_t)m*YS + 5];
                }
            }
        }

        // ---- P1: gate MFMAs (each wave: its r,z,n col-tiles, K=256, hi/lo A) ----
        f16x aR = zf16(), aZ = zf16(), aN = zf16();
        {
            const unsigned* bRp = wpg + ((size_t)((wid*3 + 0)*16)*64 + lane)*4;
            const unsigned* bZp = wpg + ((size_t)((wid*3 + 1)*16)*64 + lane)*4;
            const unsigned* bNp = wpg + ((size_t)((wid*3 + 2)*16)*64 + lane)*4;
#pragma unroll 4
            for (int kb = 0; kb < 16; ++kb){
                const bf8 br = ldg4(bRp + kb*256);
                const bf8 bz = ldg4(bZp + kb*256);
                const bf8 bn = ldg4(bNp + kb*256);
                const bf8 ah = ldfrag(hA_hi, kb*64 + lane);
                const bf8 al = ldfrag(hA_lo, kb*64 + lane);
                aR = MFMA32(ah, br, aR, 0,0,0); aR = MFMA32(al, br, aR, 0,0,0);
                aZ = MFMA32(ah, bz, aZ, 0,0,0); aZ = MFMA32(al, bz, aZ, 0,0,0);
                aN = MFMA32(ah, bn, aN, 0,0,0); aN = MFMA32(al, bn, aN, 0,0,0);
            }
        }
        if (wid >= 3 && wid < 6){   // hc gates (K=32): wave 3+g3 -> gate g3
            const int g3 = wid - 3;
            f16x cacc = zf16();
#pragma unroll
            for (int kb = 0; kb < 2; ++kb){
                const bf8 ah = ldfrag(cf_hi, kb*64 + lane);
                const bf8 al = ldfrag(cf_lo, kb*64 + lane);
                const bf8 wh = ldg4(hch + ((g3*2 + kb)*64 + lane)*4);
                const bf8 wl = ldg4(hcl + ((g3*2 + kb)*64 + lane)*4);
                cacc = MFMA32(ah, wh, cacc, 0,0,0);
                cacc = MFMA32(ah, wl, cacc, 0,0,0);
                cacc = MFMA32(al, wh, cacc, 0,0,0);
            }
#pragma unroll
            for (int q = 0; q < 16; ++q){
                const int row = (q&3) + ((q>>2)<<3) + (half<<2);
                exch[g3*1024 + row*32 + ln31] = cacc[q];
            }
        }
        __syncthreads();

        // ---- P2: GRU combine in registers -> h2 -> hA frags; wave 7: hc combine ----
#pragma unroll
        for (int q = 0; q < 16; ++q){
            const int obj = (q&3) + ((q>>2)<<3) + (half<<2);
            const float rv = sigmoid_(aR[q] + gr[q]);
            const float zv = sigmoid_(aZ[q] + gz[q]);
            const float nv = tanhf(gn[q] + rv*(aN[q] + bnd));
            const float hv = hreg[q];
            const float hnv = (1.f - zv)*nv + zv*hv;
            const float h2 = (actf[obj] > 0.f) ? hnv : hv;
            hreg[q] = h2;
            const int sl = aslot(obj, dd);
            const unsigned hb = bf16b(h2), lb = bf16b(h2 - bf16f(hb));
            hA_hi[sl] = (unsigned short)hb; hA_lo[sl] = (unsigned short)lb;
        }
        if (wid == 7){
#pragma unroll
            for (int q = 0; q < 16; ++q){
                const int obj = (q&3) + ((q>>2)<<3) + (half<<2);
                float xr = 0.f, xz = 0.f, xn = 0.f;
                if (obj < 30){
                    const float* gp = gxc + (size_t)(m0 + obj)*96 + ln31;
                    xr = gp[0]; xz = gp[32]; xn = gp[64];
                }
                const float rv = sigmoid_(exch[obj*32 + ln31] + xr);
                const float zv = sigmoid_(exch[1024 + obj*32 + ln31] + xz);
                const float nv = tanhf(xn + rv*(exch[2048 + obj*32 + ln31] + bnc));
                const float hcv = hcreg[q];
                const float cnv = (1.f - zv)*nv + zv*hcv;
                const float c2 = (actf[obj] > 0.f) ? cnv : hcv;
                hcreg[q] = c2;
                const int sl = aslot(obj, ln31);
                const unsigned hb = bf16b(c2), lb = bf16b(c2 - bf16f(hb));
                cf_hi[sl] = (unsigned short)hb; cf_lo[sl] = (unsigned short)lb;
            }
        }
        __syncthreads();

        // ---- P3: scores (w0-2) || heads (w3,4) || hc scores (w5) ----
        if (wid < 3){
            f16x s = zf16();
#pragma unroll 4
            for (int kb = 0; kb < 16; ++kb){
                const bf8 ah = ldfrag(hA_hi, kb*64 + lane);
                const bf8 al = ldfrag(hA_lo, kb*64 + lane);
                if (wid == 0)      s = MFMA32(ah, ah, s, 0,0,0);
                else if (wid == 1) s = MFMA32(ah, al, s, 0,0,0);
                else               s = MFMA32(al, ah, s, 0,0,0);
            }
#pragma unroll
            for (int q = 0; q < 16; ++q){
                const int row = (q&3) + ((q>>2)<<3) + (half<<2);
                exch[wid*1024 + row*32 + ln31] = s[q];
            }
        } else if (wid < 5){
            const int nt = wid - 3;
            f16x h1 = zf16(), h2v = zf16(), h3 = zf16();
#pragma unroll 4
            for (int kb = 0; kb < 16; ++kb){
                const bf8 ah = ldfrag(hA_hi, kb*64 + lane);
                const bf8 al = ldfrag(hA_lo, kb*64 + lane);
                const bf8 wh = ldg4(hdh + ((nt*18 + kb)*64 + lane)*4);
                const bf8 wl = ldg4(hdl + ((nt*18 + kb)*64 + lane)*4);
                h1 = MFMA32(ah, wh, h1, 0,0,0);
                h2v = MFMA32(al, wh, h2v, 0,0,0);
                h3 = MFMA32(ah, wl, h3, 0,0,0);
            }
#pragma unroll
            for (int kb = 16; kb < 18; ++kb){
                const bf8 ah = ldfrag(cf_hi, (kb-16)*64 + lane);
                const bf8 al = ldfrag(cf_lo, (kb-16)*64 + lane);
                const bf8 wh = ldg4(hdh + ((nt*18 + kb)*64 + lane)*4);
                const bf8 wl = ldg4(hdl + ((nt*18 + kb)*64 + lane)*4);
                h1 = MFMA32(ah, wh, h1, 0,0,0);
                h2v = MFMA32(al, wh, h2v, 0,0,0);
                h3 = MFMA32(ah, wl, h3, 0,0,0);
            }
            const int d = nt*32 + ln31;
            if (d < 37){
#pragma unroll
                for (int q = 0; q < 16; ++q){
                    const int obj = (q&3) + ((q>>2)<<3) + (half<<2);
                    if (obj < 30) pbl[obj*40 + d] = h1[q] + h2v[q] + h3[q];
                }
            }
        } else if (wid == 5){
            f16x s = zf16();
#pragma unroll
            for (int kb = 0; kb < 2; ++kb){
                const bf8 ah = ldfrag(cf_hi, kb*64 + lane);
                const bf8 al = ldfrag(cf_lo, kb*64 + lane);
                s = MFMA32(ah, ah, s, 0,0,0);
                s = MFMA32(ah, al, s, 0,0,0);
                s = MFMA32(al, ah, s, 0,0,0);
            }
#pragma unroll
            for (int q = 0; q < 16; ++q){
                const int row = (q&3) + ((q>>2)<<3) + (half<<2);
                exch[3072 + row*32 + ln31] = s[q];
            }
        }
        __syncthreads();

        // ---- P4: softmaxes (w0: h, w1: hc) || losses (w2-7) ----
        if (wid == 0){
            if (lane < 30){
                float sv[30]; float mx = -1e30f;
#pragma unroll
                for (int j = 0; j < 30; ++j){
                    float x = exch[lane*32 + j] + exch[1024 + lane*32 + j] + exch[2048 + lane*32 + j];
                    x = (actf[j] > 0.f) ? x * 0.0625f : -1e9f;
                    sv[j] = x; mx = fmaxf(mx, x);
                }
                float sum = 0.f;
#pragma unroll
                for (int j = 0; j < 30; ++j){ sv[j] = expf(sv[j] - mx); sum += sv[j]; }
                const float inv = 1.f / sum;
#pragma unroll
                for (int j = 0; j < 32; ++j){
                    const float w = (j < 30) ? sv[j]*inv : 0.f;
                    const unsigned hb = bf16b(w), lb = bf16b(w - bf16f(hb));
                    const int sl = aslot(lane, j);
                    wf_hi[sl] = (unsigned short)hb; wf_lo[sl] = (unsigned short)lb;
                }
            }
        } else if (wid == 1){
            if (lane < 30){
                float sv[30]; float mx = -1e30f;
#pragma unroll
                for (int j = 0; j < 30; ++j){
                    float x = exch[3072 + lane*32 + j];
                    x = (actf[j] > 0.f) ? x * 0.17677669529663687f : -1e9f;
                    sv[j] = x; mx = fmaxf(mx, x);
                }
                float sum = 0.f;
#pragma unroll
                for (int j = 0; j < 30; ++j){ sv[j] = expf(sv[j] - mx); sum += sv[j]; }
                const float inv = 1.f / sum;
#pragma unroll
                for (int j = 0; j < 32; ++j){
                    const float w = (j < 30) ? sv[j]*inv : 0.f;
                    const unsigned hb = bf16b(w), lb = bf16b(w - bf16f(hb));
                    const int sl = aslot(lane, j);
                    cwf_hi[sl] = (unsigned short)hb; cwf_lo[sl] = (unsigned short)lb;
                }
            }
        } else {
#pragma unroll
            for (int r3 = 0; r3 < 3; ++r3){
                if (lval[r3]){
                    const int obj = lobj[r3], d = ldc[r3];
                    if (actf[obj] > 0.f){
                        if (d < 36){
                            const float df = pbl[obj*40 + d] + ppb[r3] - pfu[r3];
                            const float ad = fabsf(df);
                            bacc += ((ad < 1.f) ? 0.5f*df*df : ad - 0.5f) * (1.f/36.f);
                        } else {
                            const float l = pbl[obj*40 + 36] + ppb[r3];
                            oacc += 0.05f * (fmaxf(l, 0.f) - l*ptg + log1pf(expf(-fabsf(l))));
                        }
                    }
                }
            }
        }
        __syncthreads();

        // ---- P5: attention out (all waves, own dims) || wave7: hc attn out ----
        {
            f16x ao = zf16();
#pragma unroll
            for (int kb2 = 0; kb2 < 2; ++kb2){
                const bf8 wh = ldfrag(wf_hi, kb2*64 + lane);
                const bf8 wl = ldfrag(wf_lo, kb2*64 + lane);
                const int base = ((dd>>4)*64 + kb2*16 + (half<<3) + ((dd>>3)&1)*32)*8 + (dd&7);
                const bf8 bh = gather8(hA_hi, base);
                const bf8 bl = gather8(hA_lo, base);
                ao = MFMA32(wh, bh, ao, 0,0,0);
                ao = MFMA32(wh, bl, ao, 0,0,0);
                ao = MFMA32(wl, bh, ao, 0,0,0);
            }
#pragma unroll
            for (int q = 0; q < 16; ++q){
                const int obj = (q&3) + ((q>>2)<<3) + (half<<2);
                const float v = (actf[obj] > 0.f) ? ao[q] : hreg[q];
                hreg[q] = v;
                const int sl = aslot(obj, dd);
                const unsigned hb = bf16b(v), lb = bf16b(v - bf16f(hb));
                hA_hi[sl] = (unsigned short)hb; hA_lo[sl] = (unsigned short)lb;
            }
        }
        if (wid == 7){
            f16x co = zf16();
#pragma unroll
            for (int kb2 = 0; kb2 < 2; ++kb2){
                const bf8 wh = ldfrag(cwf_hi, kb2*64 + lane);
                const bf8 wl = ldfrag(cwf_lo, kb2*64 + lane);
                const int base = ((ln31>>4)*64 + kb2*16 + (half<<3) + ((ln31>>3)&1)*32)*8 + (ln31&7);
                const bf8 bh = gather8(cf_hi, base);
                const bf8 bl = gather8(cf_lo, base);
                co = MFMA32(wh, bh, co, 0,0,0);
                co = MFMA32(wh, bl, co, 0,0,0);
                co = MFMA32(wl, bh, co, 0,0,0);
            }
#pragma unroll
            for (int q = 0; q < 16; ++q){
                const int obj = (q&3) + ((q>>2)<<3) + (half<<2);
                const float v = (actf[obj] > 0.f) ? co[q] : hcreg[q];
                hcreg[q] = v;
                const int sl = aslot(obj, ln31);
                const unsigned hb = bf16b(v), lb = bf16b(v - bf16f(hb));
                cf_hi[sl] = (unsigned short)hb; cf_lo[sl] = (unsigned short)lb;
            }
        }
        __syncthreads();
    }

    // ---- final reduce ----
#pragma unroll
    for (int o = 1; o < 64; o <<= 1){ bacc += __shfl_xor(bacc, o); oacc += __shfl_xor(oacc, o); }
    if (lane == 0){ red[wid] = bacc; red[8 + wid] = oacc; }
    __syncthreads();
    if (tid == 0){
        float b = 0.f, o = 0.f;
        for (int i = 0; i < 8; ++i){ b += red[i]; o += red[8 + i]; }
        out[0] = o + 1.3f * b;
    }
}

// ---------------- launch ----------------
extern "C" void kernel_launch(void* const* d_in, const int* in_sizes, int n_in,
                              void* d_out, int out_size, void* d_ws, size_t ws_size,
                              hipStream_t stream) {
    (void)in_sizes; (void)n_in; (void)out_size; (void)ws_size;
    const float* y      = (const float*)d_in[1];
    const float* flow   = (const float*)d_in[3];
    const float* W_rgb  = (const float*)d_in[4];
    const float* b_rgb  = (const float*)d_in[5];
    const float* W_bb   = (const float*)d_in[6];
    const float* b_bb   = (const float*)d_in[7];
    const float* W_dd   = (const float*)d_in[8];
    const float* b_dd   = (const float*)d_in[9];
    const float* W_proj = (const float*)d_in[10];
    const float* b_proj = (const float*)d_in[11];
    const float* Wx_c   = (const float*)d_in[12];
    const float* Wh_c   = (const float*)d_in[13];
    const float* bx_c   = (const float*)d_in[14];
    const float* bh_c   = (const float*)d_in[15];
    const float* Wx_g   = (const float*)d_in[16];
    const float* Wh_g   = (const float*)d_in[17];
    const float* bx_g   = (const float*)d_in[18];
    const float* bh_g   = (const float*)d_in[19];
    const float* W_out  = (const float*)d_in[20];
    const float* b_out  = (const float*)d_in[21];
    const float* W_pbox = (const float*)d_in[22];
    const float* b_pbox = (const float*)d_in[23];
    float* out = (float*)d_out;

    float* base = (float*)d_ws;
    size_t off = 0;
    float* rgb    = base + off; off += (size_t)5921 * 256;
    float* gxg    = base + off; off += (size_t)5730 * 768;
    float* gxc    = base + off; off += (size_t)5730 * 96;
    float* pboxb  = base + off; off += (size_t)5730 * 36;
    float* logitb = base + off; off += 5760;
    float* biasg  = base + off; off += 768;
    float* biasc  = base + off; off += 96;
    unsigned* wpg = (unsigned*)(base + off); off += 98304;   // 24*16*64*4
    unsigned* hdh = (unsigned*)(base + off); off += 9216;    // 2*18*64*4
    unsigned* hdl = (unsigned*)(base + off); off += 9216;
    unsigned* hch = (unsigned*)(base + off); off += 1536;    // 3*2*64*4
    unsigned* hcl = (unsigned*)(base + off); off += 1536;

    prep_bias<<<1, 768, 0, stream>>>(bx_g, bh_g, bx_c, bh_c, biasg, biasc);
    prep_wg<<<384, 256, 0, stream>>>(Wh_g, wpg);
    prep_hd<<<36, 256, 0, stream>>>(W_pbox, W_out, hdh, hdl);
    prep_hcw<<<6, 256, 0, stream>>>(Wh_c, hch, hcl);

    gemm_tiled<false, true><<<dim3(4, 93), 256, 0, stream>>>(flow, W_rgb, b_rgb, rgb, 5921, 256, 4096);
    gemm_tiled<true, false><<<dim3(12, 90), 256, 0, stream>>>(rgb, Wx_g, biasg, gxg, 5730, 768, 512);
    precomp_kernel<<<5730, 256, 0, stream>>>(y, W_bb, b_bb, W_dd, b_dd, W_proj, b_proj,
                                             Wx_c, biasc, W_pbox, b_pbox, W_out, b_out,
                                             gxc, pboxb, logitb);
    seq1<<<1, 512, 0, stream>>>(y, gxg, gxc, pboxb, logitb, wpg, hdh, hdl, hch, hcl,
                                bh_g, bh_c, out);
}

// Round 4
// 4140.256 us; speedup vs baseline: 1.9571x; 1.9571x over previous
//
#include <hip/hip_runtime.h>
#include <math.h>
#include <stdint.h>

// ---------------- constants ----------------
#define T_STEPS 191      // 200 - 9
#define NB1 31
#define YS 13            // y feature stride
#define NBLK 8

// ---------------- MFMA types/helpers ----------------
typedef short bf8 __attribute__((ext_vector_type(8)));    // 8 bf16 (4 VGPRs)
typedef float f16x __attribute__((ext_vector_type(16)));  // 32x32 accumulator

#define MFMA32 __builtin_amdgcn_mfma_f32_32x32x16_bf16

__device__ __forceinline__ float sigmoid_(float x) { return 1.f / (1.f + expf(-x)); }

__device__ __forceinline__ unsigned bf16b(float x){        // RNE fp32->bf16 bits
  unsigned u = __float_as_uint(x);
  return (u + 0x7fffu + ((u>>16)&1u)) >> 16;
}
__device__ __forceinline__ float bf16f(unsigned b){ return __uint_as_float(b<<16); }

__device__ __forceinline__ bf8 ldfrag(const unsigned short* p, int slot){
  uint4 u = *reinterpret_cast<const uint4*>(p + slot*8);   // ds_read_b128
  return __builtin_bit_cast(bf8, u);
}
__device__ __forceinline__ bf8 ldg4(const unsigned* p){
  uint4 u = *reinterpret_cast<const uint4*>(p);            // 16B load (global or LDS)
  return __builtin_bit_cast(bf8, u);
}
// transposed gather: 8 bf16 at stride 8 ushorts (consecutive m in A-layout)
__device__ __forceinline__ bf8 gather8(const unsigned short* fr, int base){
  unsigned w0 = (unsigned)fr[base]    | ((unsigned)fr[base+8]<<16);
  unsigned w1 = (unsigned)fr[base+16] | ((unsigned)fr[base+24]<<16);
  unsigned w2 = (unsigned)fr[base+32] | ((unsigned)fr[base+40]<<16);
  unsigned w3 = (unsigned)fr[base+48] | ((unsigned)fr[base+56]<<16);
  uint4 u; u.x=w0; u.y=w1; u.z=w2; u.w=w3;
  return __builtin_bit_cast(bf8, u);
}
__device__ __forceinline__ f16x zf16(){
  f16x v;
#pragma unroll
  for (int q=0;q<16;++q) v[q]=0.f;
  return v;
}
// A-layout slot for element (m, k):  ((k>>4)*64 + m + ((k>>3)&1)*32)*8 + (k&7)
__device__ __forceinline__ int aslot(int m, int k){
  return ((k>>4)*64 + m + ((k>>3)&1)*32)*8 + (k&7);
}

// ---- cross-XCD coherent ops (MALL): protocol proven in R0/R2 ----
__device__ __forceinline__ void store_dwx2_mall(unsigned* p, unsigned a, unsigned b){
    const unsigned long long v = ((unsigned long long)b << 32) | (unsigned long long)a;
    asm volatile("global_store_dwordx2 %0, %1, off sc0 sc1"
                 :: "v"((uintptr_t)p), "v"(v) : "memory");
}
__device__ __forceinline__ void atomic_inc_mall(unsigned* p) {
    asm volatile("global_atomic_add %0, %1, off sc1"
                 :: "v"((uintptr_t)p), "v"(1u) : "memory");
}
__device__ __forceinline__ unsigned load_u32_mall(const unsigned* p) {
    unsigned v;
    asm volatile("global_load_dword %0, %1, off sc0 sc1\n\ts_waitcnt vmcnt(0)"
                 : "=v"(v) : "v"((uintptr_t)p) : "memory");
    return v;
}

// ---------------- tiled fp32 GEMM: C = act(A @ B + bias) (unchanged, proven) ----------------
template <bool GATHER, bool RELU>
__global__ __launch_bounds__(256) void gemm_tiled(
    const float* __restrict__ A, const float* __restrict__ B,
    const float* __restrict__ bias, float* __restrict__ C,
    int M, int N, int K)
{
    __shared__ float As[16][65];
    __shared__ float Bs[16][65];
    const int tid = threadIdx.x;
    const int tm = tid >> 4, tn = tid & 15;
    const int rowBase = blockIdx.y * 64;
    const int colBase = blockIdx.x * 64;
    float acc[4][4] = {};
    for (int kt = 0; kt < K; kt += 16) {
        #pragma unroll
        for (int l = 0; l < 4; ++l) {
            const int idx = tid + l * 256;
            const int kk = idx & 15, rr = idx >> 4;
            const int row = rowBase + rr;
            float v = 0.f;
            if (row < M) {
                if (GATHER) {
                    const int t = row / 30, i = row - t * 30;
                    const int k = kt + kk;
                    const int src = (k < 256) ? ((t * NB1 + i + 1) * 256 + k)
                                              : (t * NB1 * 256 + (k - 256));
                    v = A[src];
                } else {
                    v = A[(size_t)row * K + kt + kk];
                }
            }
            As[kk][rr] = v;
            const int nn = idx & 63, k2 = idx >> 6;
            Bs[k2][nn] = B[(size_t)(kt + k2) * N + colBase + nn];
        }
        __syncthreads();
        #pragma unroll
        for (int kk = 0; kk < 16; ++kk) {
            float a[4], b[4];
            #pragma unroll
            for (int i = 0; i < 4; ++i) a[i] = As[kk][tm * 4 + i];
            #pragma unroll
            for (int j = 0; j < 4; ++j) b[j] = Bs[kk][tn * 4 + j];
            #pragma unroll
            for (int i = 0; i < 4; ++i)
                #pragma unroll
                for (int j = 0; j < 4; ++j)
                    acc[i][j] = fmaf(a[i], b[j], acc[i][j]);
        }
        __syncthreads();
    }
    #pragma unroll
    for (int i = 0; i < 4; ++i) {
        const int row = rowBase + tm * 4 + i;
        if (row < M) {
            #pragma unroll
            for (int j = 0; j < 4; ++j) {
                const int col = colBase + tn * 4 + j;
                float v = acc[i][j] + bias[col];
                if (RELU) v = fmaxf(v, 0.f);
                C[(size_t)row * N + col] = v;
            }
        }
    }
}

// ---------------- prep: gate weights -> B-fragment layout, cols permuted ----------------
// wpg index = ((nt*16 + kb)*64 + lane)*4 + j ; nt = 3*g + gate (g = 32-dim group)
__global__ __launch_bounds__(256) void prep_wg(const float* __restrict__ Whg,
                                               unsigned* __restrict__ wpg)
{
    const int idx = blockIdx.x * 256 + threadIdx.x;     // < 24*16*64*4 = 98304
    const int j  = idx & 3;
    const int l  = (idx >> 2) & 63;
    const int kb = (idx >> 8) & 15;
    const int nt = idx >> 12;                            // 0..23
    const int g = nt / 3, gate = nt - g * 3;
    const int col = gate * 256 + g * 32 + (l & 31);
    const int k2 = kb * 8 + ((l >> 5) << 2) + j;
    const unsigned lo = bf16b(Whg[(size_t)(2 * k2) * 768 + col]);
    const unsigned hi = bf16b(Whg[(size_t)(2 * k2 + 1) * 768 + col]);
    wpg[idx] = lo | (hi << 16);
}

// heads B (K=288: hn 0..255 -> Wpbox rows 0..255 / Wout; hc 256..287 -> rows 512..543)
__global__ __launch_bounds__(256) void prep_hd(const float* __restrict__ Wpbox,
                                               const float* __restrict__ Wout,
                                               unsigned* __restrict__ hdh,
                                               unsigned* __restrict__ hdl)
{
    const int idx = blockIdx.x * 256 + threadIdx.x;     // < 2*18*64*4 = 9216
    if (idx >= 9216) return;
    const int j = idx & 3;
    const int l = (idx >> 2) & 63;
    const int kbnt = idx >> 8;                           // 0..35
    const int kb = kbnt % 18, nt = kbnt / 18;
    const int d = nt * 32 + (l & 31);
    const int k0 = kb * 16 + ((l >> 5) << 3) + 2 * j;
    float v0 = 0.f, v1 = 0.f;
    if (d < 37) {
        const int r0 = (k0 < 256) ? k0 : 512 + (k0 - 256);
        const int r1 = (k0 + 1 < 256) ? (k0 + 1) : 512 + (k0 + 1 - 256);
        v0 = (d < 36) ? Wpbox[(size_t)r0 * 36 + d] : Wout[r0];
        v1 = (d < 36) ? Wpbox[(size_t)r1 * 36 + d] : Wout[r1];
    }
    const unsigned h0 = bf16b(v0), h1 = bf16b(v1);
    const unsigned l0 = bf16b(v0 - bf16f(h0)), l1 = bf16b(v1 - bf16f(h1));
    hdh[idx] = h0 | (h1 << 16);
    hdl[idx] = l0 | (l1 << 16);
}

// hc gate weights (nt = gate): index = ((nt*2 + kb)*64 + lane)*4 + j
__global__ __launch_bounds__(256) void prep_hcw(const float* __restrict__ Whc,
                                                unsigned* __restrict__ hch,
                                                unsigned* __restrict__ hcl)
{
    const int idx = blockIdx.x * 256 + threadIdx.x;     // < 3*2*64*4 = 1536
    if (idx >= 1536) return;
    const int j = idx & 3;
    const int l = (idx >> 2) & 63;
    const int kb = (idx >> 8) & 1;
    const int nt = idx >> 9;                             // 0..2
    const int col = nt * 32 + (l & 31);
    const int k0 = kb * 16 + ((l >> 5) << 3) + 2 * j;
    const float v0 = Whc[k0 * 96 + col];
    const float v1 = Whc[(k0 + 1) * 96 + col];
    const unsigned h0 = bf16b(v0), h1 = bf16b(v1);
    const unsigned l0 = bf16b(v0 - bf16f(h0)), l1 = bf16b(v1 - bf16f(h1));
    hch[idx] = h0 | (h1 << 16);
    hcl[idx] = l0 | (l1 << 16);
}

// combined biases: r/z gates get bx+bh (additive), n gate keeps bx only
__global__ void prep_bias(const float* __restrict__ bxg, const float* __restrict__ bhg,
                          const float* __restrict__ bxc, const float* __restrict__ bhc,
                          float* __restrict__ biasg, float* __restrict__ biasc)
{
    const int t = threadIdx.x;
    if (t < 768) biasg[t] = bxg[t] + (t < 512 ? bhg[t] : 0.f);
    if (t < 96)  biasc[t] = bxc[t] + (t < 64 ? bhc[t] : 0.f);
}

// ---------------- per-(t,obj) small precompute (unchanged, proven) ----------------
__global__ __launch_bounds__(256) void precomp_kernel(
    const float* __restrict__ y,
    const float* __restrict__ Wbb, const float* __restrict__ bbb,
    const float* __restrict__ Wdd, const float* __restrict__ bdd,
    const float* __restrict__ Wproj, const float* __restrict__ bproj,
    const float* __restrict__ Wxc, const float* __restrict__ biasc,
    const float* __restrict__ Wpbox, const float* __restrict__ bpbox,
    const float* __restrict__ Wout, const float* __restrict__ bout,
    float* __restrict__ gxc, float* __restrict__ pbox_b, float* __restrict__ logit_b)
{
    const int m = blockIdx.x;
    const int tid = threadIdx.x;
    __shared__ float bf[256], df[256], xcs[32], yl[16];
    if (tid < YS) yl[tid] = y[m * YS + tid];
    __syncthreads();
    const float invnorm[4] = {1.f/1920.f, 1.f/1200.f, 1.f/1920.f, 1.f/1200.f};
    {
        float s = bbb[tid];
        s = fmaf(yl[1] * invnorm[0], Wbb[0 * 256 + tid], s);
        s = fmaf(yl[2] * invnorm[1], Wbb[1 * 256 + tid], s);
        s = fmaf(yl[3] * invnorm[2], Wbb[2 * 256 + tid], s);
        s = fmaf(yl[4] * invnorm[3], Wbb[3 * 256 + tid], s);
        s = fmaf(yl[6],              Wbb[4 * 256 + tid], s);
        bf[tid] = fmaxf(s, 0.f);
    }
    {
        float s = bdd[tid];
        #pragma unroll
        for (int k = 0; k < 6; ++k) s = fmaf(yl[7 + k], Wdd[k * 256 + tid], s);
        df[tid] = fmaxf(s, 0.f);
    }
    __syncthreads();
    {
        const int c = tid >> 3, p = tid & 7;
        float s = 0.f;
        for (int k = p; k < 256; k += 8) s = fmaf(df[k], Wproj[k * 32 + c], s);
        s += __shfl_xor(s, 1); s += __shfl_xor(s, 2); s += __shfl_xor(s, 4);
        if (p == 0) xcs[c] = s + bproj[c];
    }
    __syncthreads();
    if (tid < 96) {
        float s = biasc[tid];
        #pragma unroll
        for (int k = 0; k < 32; ++k) s = fmaf(xcs[k], Wxc[k * 96 + tid], s);
        gxc[m * 96 + tid] = s;
    }
    {
        const int d = tid >> 2, p = tid & 3;
        if (d < 37) {
            float s = 0.f;
            if (d < 36) {
                for (int k = p; k < 256; k += 4) s = fmaf(bf[k], Wpbox[(256 + k) * 36 + d], s);
            } else {
                for (int k = p; k < 256; k += 4) s = fmaf(bf[k], Wout[256 + k], s);
            }
            s += __shfl_xor(s, 1); s += __shfl_xor(s, 2);
            if (p == 0) {
                if (d < 36) pbox_b[m * 36 + d] = s + bpbox[d];
                else        logit_b[m] = s + bout[0];
            }
        }
    }
}

// ---------------- 8-block MFMA recurrence, minimal dense h2 exchange ----------------
// Block b: gate MFMA for its 32 dims only (weights LDS-resident). Exchange = packed
// h2 frags, coalesced dwordx2 publish / dwordx4 readback. hc path + heads + attn
// computed redundantly per block from the full post-exchange h2. Losses split by obj.
__global__ __launch_bounds__(512, 1) void seqx(
    const float* __restrict__ y,
    const float* __restrict__ gxg,      // 5730 x 768 (bias-combined x-side)
    const float* __restrict__ gxc,      // 5730 x 96
    const float* __restrict__ pbox_b,   // 5730 x 36
    const float* __restrict__ logit_b,  // 5730
    const unsigned* __restrict__ wpg,   // gate B frags (bf16 pairs), 24*4096
    const unsigned* __restrict__ hdh, const unsigned* __restrict__ hdl, // heads B hi/lo
    const unsigned* __restrict__ hch, const unsigned* __restrict__ hcl, // hc B hi/lo
    const float* __restrict__ bhg,      // 768 (n-part used)
    const float* __restrict__ bhc,      // 96 (n-part used)
    unsigned* __restrict__ h2x,         // 2 x 8192 packed hi|lo h2 frags
    unsigned* __restrict__ bar,
    float* __restrict__ parts)          // 16
{
    const int tid = threadIdx.x;
    const int bb = blockIdx.x;
    const int lane = tid & 63, wid = tid >> 6;
    const int half = lane >> 5, ln31 = lane & 31;

    __shared__ __align__(16) unsigned wgl[12288];                     // own gate B frags
    __shared__ __align__(16) unsigned short hA_hi[8192], hA_lo[8192]; // full h/h2 frags
    __shared__ __align__(16) unsigned short cf_hi[1024],  cf_lo[1024];  // hc/hc2 frags
    __shared__ __align__(16) unsigned short wf_hi[1024],  wf_lo[1024];  // attn w frags
    __shared__ __align__(16) unsigned short cwf_hi[1024], cwf_lo[1024]; // hc attn w frags
    __shared__ float exch[6144];   // gate outs (P1) / scores (P3)
    __shared__ float gxgs[2880];   // x-side gate slice [obj][96] (own dims)
    __shared__ float gxcs[2880];   // hc x-side slice [obj][96]
    __shared__ float hcst[1056];   // hc state fp32 [obj][33]
    __shared__ float pbl[1280];    // head outputs [obj][40]
    __shared__ float actf[32], bhnl[32], bhcl[32], red[16];

    // ---- pre-loop staging ----
    {
        const unsigned* wsrc = wpg + (size_t)(3 * bb) * 4096;
        for (int i = tid; i < 12288; i += 512) wgl[i] = wsrc[i];
    }
    for (int i = tid; i < 8192; i += 512){ hA_hi[i] = 0; hA_lo[i] = 0; }
    for (int i = tid; i < 1024; i += 512){
        cf_hi[i]=0; cf_lo[i]=0; wf_hi[i]=0; wf_lo[i]=0; cwf_hi[i]=0; cwf_lo[i]=0;
    }
    for (int i = tid; i < 1056; i += 512) hcst[i] = 0.f;
    if (tid < 32){ bhnl[tid] = bhg[512 + bb*32 + tid]; bhcl[tid] = bhc[64 + tid]; }
    float bacc = 0.f, oacc = 0.f;
    __syncthreads();

    for (int t = 0; t < T_STEPS; ++t){
        const int m0 = t * 30;
        const int dbuf = t & 1;
        unsigned* h2b = h2x + dbuf * 8192;

        // ---- P0: act flags; issue x-side staging loads into bounded regs ----
        if (tid < 32) actf[tid] = (tid < 30 && y[(size_t)(m0 + tid) * YS] != 0.f) ? 1.f : 0.f;
        float4 sg0, sg1, sc0v, sc1v;
        const bool hasg = (tid < 360);
        if (hasg){
            { const int i = tid;       const int obj = i/12, r12 = i - obj*12;
              sg0 = *(const float4*)(gxg + (size_t)(m0+obj)*768 + (r12>>2)*256 + bb*32 + (r12&3)*8); }
            { const int i = tid;       const int obj = i/12, r12 = i - obj*12;
              sg1 = *(const float4*)(gxg + (size_t)(m0+obj)*768 + (r12>>2)*256 + bb*32 + (r12&3)*8 + 4); }
            { const int i = tid;       const int obj = i/12, c12 = i - obj*12;
              sc0v = *(const float4*)(gxc + (size_t)(m0+obj)*96 + c12*8); }
            { const int i = tid;       const int obj = i/12, c12 = i - obj*12;
              sc1v = *(const float4*)(gxc + (size_t)(m0+obj)*96 + c12*8 + 4); }
        }

        // ---- P1: gate MFMAs. waves 0-2: h-gates (own dims, K=256 hi/lo).
        //          waves 3-5: hc gates (K=32). waves 6-7 idle. ----
        if (wid < 3){
            f16x acc = zf16();
            const unsigned* wb = wgl + wid * 4096;
#pragma unroll 4
            for (int kb = 0; kb < 16; ++kb){
                const bf8 bw = ldg4(wb + (kb*64 + lane)*4);
                const bf8 ah = ldfrag(hA_hi, kb*64 + lane);
                const bf8 al = ldfrag(hA_lo, kb*64 + lane);
                acc = MFMA32(ah, bw, acc, 0,0,0);
                acc = MFMA32(al, bw, acc, 0,0,0);
            }
#pragma unroll
            for (int q = 0; q < 16; ++q){
                const int row = (q&3) + ((q>>2)<<3) + (half<<2);
                exch[wid*1024 + row*32 + ln31] = acc[q];
            }
        } else if (wid < 6){
            const int g3 = wid - 3;
            f16x cacc = zf16();
#pragma unroll
            for (int kb = 0; kb < 2; ++kb){
                const bf8 ah = ldfrag(cf_hi, kb*64 + lane);
                const bf8 al = ldfrag(cf_lo, kb*64 + lane);
                const bf8 wh = ldg4(hch + ((g3*2 + kb)*64 + lane)*4);
                const bf8 wl = ldg4(hcl + ((g3*2 + kb)*64 + lane)*4);
                cacc = MFMA32(ah, wh, cacc, 0,0,0);
                cacc = MFMA32(ah, wl, cacc, 0,0,0);
                cacc = MFMA32(al, wh, cacc, 0,0,0);
            }
#pragma unroll
            for (int q = 0; q < 16; ++q){
                const int row = (q&3) + ((q>>2)<<3) + (half<<2);
                exch[(3+g3)*1024 + row*32 + ln31] = cacc[q];
            }
        }
        // land staged x-side into LDS
        if (hasg){
            const int obj = tid/12, r12 = tid - obj*12;
            *(float4*)(gxgs + obj*96 + r12*8)     = sg0;
            *(float4*)(gxgs + obj*96 + r12*8 + 4) = sg1;
            *(float4*)(gxcs + obj*96 + r12*8)     = sc0v;
            *(float4*)(gxcs + obj*96 + r12*8 + 4) = sc1v;
        }
        __syncthreads();

        // ---- P2a: h GRU combine (own dims) -> hA own-tile frags ----
        if (tid < 480){
#pragma unroll
            for (int s = 0; s < 2; ++s){
                const int e = tid*2 + s;
                const int obj = e >> 5, dim = e & 31;
                const float rv = sigmoid_(exch[obj*32 + dim]        + gxgs[obj*96 + dim]);
                const float zv = sigmoid_(exch[1024 + obj*32 + dim] + gxgs[obj*96 + 32 + dim]);
                const float nv = tanhf(gxgs[obj*96 + 64 + dim]
                                       + rv*(exch[2048 + obj*32 + dim] + bhnl[dim]));
                const int sl = aslot(obj, bb*32 + dim);
                const float h = bf16f(hA_hi[sl]) + bf16f(hA_lo[sl]);
                const float hnv = (1.f - zv)*nv + zv*h;
                const float h2 = (actf[obj] > 0.f) ? hnv : h;
                const unsigned hb = bf16b(h2), lb = bf16b(h2 - bf16f(hb));
                hA_hi[sl] = (unsigned short)hb; hA_lo[sl] = (unsigned short)lb;
            }
        }
        __syncthreads();

        // ---- P2b: publish own tile (coalesced dwordx2, MALL) || hc combine ----
        {
            const int s0 = 1024*bb + tid*2;
            const unsigned d0 = (unsigned)hA_hi[s0]   | ((unsigned)hA_lo[s0]   << 16);
            const unsigned d1 = (unsigned)hA_hi[s0+1] | ((unsigned)hA_lo[s0+1] << 16);
            store_dwx2_mall(h2b + s0, d0, d1);
        }
        if (tid < 480){
#pragma unroll
            for (int s = 0; s < 2; ++s){
                const int e = tid*2 + s;
                const int obj = e >> 5, cd = e & 31;
                const float rv = sigmoid_(exch[3072 + obj*32 + cd] + gxcs[obj*96 + cd]);
                const float zv = sigmoid_(exch[4096 + obj*32 + cd] + gxcs[obj*96 + 32 + cd]);
                const float nv = tanhf(gxcs[obj*96 + 64 + cd]
                                       + rv*(exch[5120 + obj*32 + cd] + bhcl[cd]));
                const float hc = hcst[obj*33 + cd];
                const float cnv = (1.f - zv)*nv + zv*hc;
                const float c2 = (actf[obj] > 0.f) ? cnv : hc;
                hcst[obj*33 + cd] = c2;
                const int sl = aslot(obj, cd);
                const unsigned hb = bf16b(c2), lb = bf16b(c2 - bf16f(hb));
                cf_hi[sl] = (unsigned short)hb; cf_lo[sl] = (unsigned short)lb;
            }
        }
        asm volatile("s_waitcnt vmcnt(0)" ::: "memory");
        __syncthreads();

        // ---- barrier: MALL atomic + spin (proven protocol) ----
        if (tid == 0){
            atomic_inc_mall(bar);
            const unsigned tgtc = (unsigned)(NBLK * (t + 1));
            unsigned cur;
            do { asm volatile("s_sleep 1" :::); cur = load_u32_mall(bar); } while (cur < tgtc);
        }
        __syncthreads();

        // ---- P3a: dense readback of full h2 (4 x dwordx4 per thread) ----
        {
            uint4 v0, v1, v2, v3;
            const unsigned* p0 = h2b + 0*2048 + tid*4;
            const unsigned* p1 = h2b + 1*2048 + tid*4;
            const unsigned* p2 = h2b + 2*2048 + tid*4;
            const unsigned* p3 = h2b + 3*2048 + tid*4;
            asm volatile("global_load_dwordx4 %0, %1, off sc0 sc1" : "=v"(v0) : "v"((uintptr_t)p0) : "memory");
            asm volatile("global_load_dwordx4 %0, %1, off sc0 sc1" : "=v"(v1) : "v"((uintptr_t)p1) : "memory");
            asm volatile("global_load_dwordx4 %0, %1, off sc0 sc1" : "=v"(v2) : "v"((uintptr_t)p2) : "memory");
            asm volatile("global_load_dwordx4 %0, %1, off sc0 sc1" : "=v"(v3) : "v"((uintptr_t)p3) : "memory");
            asm volatile("s_waitcnt vmcnt(0)" ::: "memory");
            const uint4 vv[4] = {v0, v1, v2, v3};
#pragma unroll
            for (int j = 0; j < 4; ++j){
                const int sl = j*2048 + tid*4;
                const unsigned dw[4] = {vv[j].x, vv[j].y, vv[j].z, vv[j].w};
#pragma unroll
                for (int k = 0; k < 4; ++k){
                    hA_hi[sl+k] = (unsigned short)(dw[k] & 0xffffu);
                    hA_lo[sl+k] = (unsigned short)(dw[k] >> 16);
                }
            }
        }
        __syncthreads();

        // ---- P3b: scores (w0-2) || heads (w3,4) || hc scores (w5) ----
        if (wid < 3){
            f16x s = zf16();
#pragma unroll 4
            for (int kb = 0; kb < 16; ++kb){
                const bf8 ah = ldfrag(hA_hi, kb*64 + lane);
                const bf8 al = ldfrag(hA_lo, kb*64 + lane);
                if (wid == 0)      s = MFMA32(ah, ah, s, 0,0,0);
                else if (wid == 1) s = MFMA32(ah, al, s, 0,0,0);
                else               s = MFMA32(al, ah, s, 0,0,0);
            }
#pragma unroll
            for (int q = 0; q < 16; ++q){
                const int row = (q&3) + ((q>>2)<<3) + (half<<2);
                exch[wid*1024 + row*32 + ln31] = s[q];
            }
        } else if (wid < 5){
            const int nt = wid - 3;
            f16x h1 = zf16(), h2v = zf16(), h3 = zf16();
#pragma unroll 4
            for (int kb = 0; kb < 16; ++kb){
                const bf8 ah = ldfrag(hA_hi, kb*64 + lane);
                const bf8 al = ldfrag(hA_lo, kb*64 + lane);
                const bf8 wh = ldg4(hdh + ((nt*18 + kb)*64 + lane)*4);
                const bf8 wl = ldg4(hdl + ((nt*18 + kb)*64 + lane)*4);
                h1 = MFMA32(ah, wh, h1, 0,0,0);
                h2v = MFMA32(al, wh, h2v, 0,0,0);
                h3 = MFMA32(ah, wl, h3, 0,0,0);
            }
#pragma unroll
            for (int kb = 16; kb < 18; ++kb){
                const bf8 ah = ldfrag(cf_hi, (kb-16)*64 + lane);
                const bf8 al = ldfrag(cf_lo, (kb-16)*64 + lane);
                const bf8 wh = ldg4(hdh + ((nt*18 + kb)*64 + lane)*4);
                const bf8 wl = ldg4(hdl + ((nt*18 + kb)*64 + lane)*4);
                h1 = MFMA32(ah, wh, h1, 0,0,0);
                h2v = MFMA32(al, wh, h2v, 0,0,0);
                h3 = MFMA32(ah, wl, h3, 0,0,0);
            }
            const int d = nt*32 + ln31;
            if (d < 37){
#pragma unroll
                for (int q = 0; q < 16; ++q){
                    const int obj = (q&3) + ((q>>2)<<3) + (half<<2);
                    if (obj < 30) pbl[obj*40 + d] = h1[q] + h2v[q] + h3[q];
                }
            }
        } else if (wid == 5){
            f16x s = zf16();
#pragma unroll
            for (int kb = 0; kb < 2; ++kb){
                const bf8 ah = ldfrag(cf_hi, kb*64 + lane);
                const bf8 al = ldfrag(cf_lo, kb*64 + lane);
                s = MFMA32(ah, ah, s, 0,0,0);
                s = MFMA32(ah, al, s, 0,0,0);
                s = MFMA32(al, ah, s, 0,0,0);
            }
#pragma unroll
            for (int q = 0; q < 16; ++q){
                const int row = (q&3) + ((q>>2)<<3) + (half<<2);
                exch[3072 + row*32 + ln31] = s[q];
            }
        }
        __syncthreads();

        // ---- P4: softmaxes (w0: h, w1: hc) || losses on own objects (w2+) ----
        if (wid == 0){
            if (lane < 30){
                float sv[30]; float mx = -1e30f;
#pragma unroll
                for (int j = 0; j < 30; ++j){
                    float x = exch[lane*32 + j] + exch[1024 + lane*32 + j] + exch[2048 + lane*32 + j];
                    x = (actf[j] > 0.f) ? x * 0.0625f : -1e9f;
                    sv[j] = x; mx = fmaxf(mx, x);
                }
                float sum = 0.f;
#pragma unroll
                for (int j = 0; j < 30; ++j){ sv[j] = expf(sv[j] - mx); sum += sv[j]; }
                const float inv = 1.f / sum;
#pragma unroll
                for (int j = 0; j < 32; ++j){
                    const float w = (j < 30) ? sv[j]*inv : 0.f;
                    const unsigned hb = bf16b(w), lb = bf16b(w - bf16f(hb));
                    const int sl = aslot(lane, j);
                    wf_hi[sl] = (unsigned short)hb; wf_lo[sl] = (unsigned short)lb;
                }
            }
        } else if (wid == 1){
            if (lane < 30){
                float sv[30]; float mx = -1e30f;
#pragma unroll
                for (int j = 0; j < 30; ++j){
                    float x = exch[3072 + lane*32 + j];
                    x = (actf[j] > 0.f) ? x * 0.17677669529663687f : -1e9f;
                    sv[j] = x; mx = fmaxf(mx, x);
                }
                float sum = 0.f;
#pragma unroll
                for (int j = 0; j < 30; ++j){ sv[j] = expf(sv[j] - mx); sum += sv[j]; }
                const float inv = 1.f / sum;
#pragma unroll
                for (int j = 0; j < 32; ++j){
                    const float w = (j < 30) ? sv[j]*inv : 0.f;
                    const unsigned hb = bf16b(w), lb = bf16b(w - bf16f(hb));
                    const int sl = aslot(lane, j);
                    cwf_hi[sl] = (unsigned short)hb; cwf_lo[sl] = (unsigned short)lb;
                }
            }
        } else {
            const int nObj = (bb == 7) ? 2 : 4;
            const int c = tid - 128;
            if (c < nObj * 37){
                const int oo = c / 37, d = c - oo*37;
                const int obj = bb*4 + oo;
                if (actf[obj] > 0.f){
                    const int m = m0 + obj;
                    if (d < 36){
                        const int s4 = d >> 2, cc = d & 3;
                        const float fn = (cc & 1) ? (1.f/1200.f) : (1.f/1920.f);
                        const float fu = y[(size_t)((t + 1 + s4)*30 + obj)*YS + 1 + cc] * fn;
                        const float df = pbl[obj*40 + d] + pbox_b[(size_t)m*36 + d] - fu;
                        const float ad = fabsf(df);
                        bacc += ((ad < 1.f) ? 0.5f*df*df : ad - 0.5f) * (1.f/36.f);
                    } else {
                        const float l = pbl[obj*40 + 36] + logit_b[m];
                        const float tg = y[(size_t)m*YS + 5];
                        oacc += 0.05f * (fmaxf(l, 0.f) - l*tg + log1pf(expf(-fabsf(l))));
                    }
                }
            }
        }
        __syncthreads();

        // ---- P5: attn out, all waves (wave w -> dim tile w) -> full h(t+1) in hA;
        //          wave 7 additionally hc attn ----
        {
            const int dd = wid*32 + ln31;
            f16x ao = zf16();
#pragma unroll
            for (int kb2 = 0; kb2 < 2; ++kb2){
                const bf8 wh = ldfrag(wf_hi, kb2*64 + lane);
                const bf8 wl = ldfrag(wf_lo, kb2*64 + lane);
                const int base = ((dd>>4)*64 + kb2*16 + (half<<3) + ((dd>>3)&1)*32)*8 + (dd&7);
                const bf8 bh = gather8(hA_hi, base);
                const bf8 bl = gather8(hA_lo, base);
                ao = MFMA32(wh, bh, ao, 0,0,0);
                ao = MFMA32(wh, bl, ao, 0,0,0);
                ao = MFMA32(wl, bh, ao, 0,0,0);
            }
#pragma unroll
            for (int q = 0; q < 16; ++q){
                const int obj = (q&3) + ((q>>2)<<3) + (half<<2);
                const int sl = aslot(obj, dd);
                const float h2v = bf16f(hA_hi[sl]) + bf16f(hA_lo[sl]);
                const float v = (actf[obj] > 0.f) ? ao[q] : h2v;
                const unsigned hb = bf16b(v), lb = bf16b(v - bf16f(hb));
                hA_hi[sl] = (unsigned short)hb; hA_lo[sl] = (unsigned short)lb;
            }
        }
        if (wid == 7){
            f16x co = zf16();
#pragma unroll
            for (int kb2 = 0; kb2 < 2; ++kb2){
                const bf8 wh = ldfrag(cwf_hi, kb2*64 + lane);
                const bf8 wl = ldfrag(cwf_lo, kb2*64 + lane);
                const int base = ((ln31>>4)*64 + kb2*16 + (half<<3) + ((ln31>>3)&1)*32)*8 + (ln31&7);
                const bf8 bh = gather8(cf_hi, base);
                const bf8 bl = gather8(cf_lo, base);
                co = MFMA32(wh, bh, co, 0,0,0);
                co = MFMA32(wh, bl, co, 0,0,0);
                co = MFMA32(wl, bh, co, 0,0,0);
            }
#pragma unroll
            for (int q = 0; q < 16; ++q){
                const int obj = (q&3) + ((q>>2)<<3) + (half<<2);
                const float v = (actf[obj] > 0.f) ? co[q] : hcst[obj*33 + ln31];
                hcst[obj*33 + ln31] = v;
                const int sl = aslot(obj, ln31);
                const unsigned hb = bf16b(v), lb = bf16b(v - bf16f(hb));
                cf_hi[sl] = (unsigned short)hb; cf_lo[sl] = (unsigned short)lb;
            }
        }
        __syncthreads();
    }

    // ---- final reduce ----
#pragma unroll
    for (int o = 1; o < 64; o <<= 1){ bacc += __shfl_xor(bacc, o); oacc += __shfl_xor(oacc, o); }
    if (lane == 0){ red[wid] = bacc; red[8 + wid] = oacc; }
    __syncthreads();
    if (tid == 0){
        float b = 0.f, o = 0.f;
        for (int i = 0; i < 8; ++i){ b += red[i]; o += red[8 + i]; }
        parts[bb] = b; parts[8 + bb] = o;
    }
}

__global__ void reduce_kernel(const float* __restrict__ parts, float* __restrict__ out) {
    if (threadIdx.x == 0) {
        float b = 0.f, o = 0.f;
        for (int i = 0; i < NBLK; ++i) { b += parts[i]; o += parts[8 + i]; }
        out[0] = o + 1.3f * b;
    }
}

// ---------------- launch ----------------
extern "C" void kernel_launch(void* const* d_in, const int* in_sizes, int n_in,
                              void* d_out, int out_size, void* d_ws, size_t ws_size,
                              hipStream_t stream) {
    (void)in_sizes; (void)n_in; (void)out_size; (void)ws_size;
    const float* y      = (const float*)d_in[1];
    const float* flow   = (const float*)d_in[3];
    const float* W_rgb  = (const float*)d_in[4];
    const float* b_rgb  = (const float*)d_in[5];
    const float* W_bb   = (const float*)d_in[6];
    const float* b_bb   = (const float*)d_in[7];
    const float* W_dd   = (const float*)d_in[8];
    const float* b_dd   = (const float*)d_in[9];
    const float* W_proj = (const float*)d_in[10];
    const float* b_proj = (const float*)d_in[11];
    const float* Wx_c   = (const float*)d_in[12];
    const float* Wh_c   = (const float*)d_in[13];
    const float* bx_c   = (const float*)d_in[14];
    const float* bh_c   = (const float*)d_in[15];
    const float* Wx_g   = (const float*)d_in[16];
    const float* Wh_g   = (const float*)d_in[17];
    const float* bx_g   = (const float*)d_in[18];
    const float* bh_g   = (const float*)d_in[19];
    const float* W_out  = (const float*)d_in[20];
    const float* b_out  = (const float*)d_in[21];
    const float* W_pbox = (const float*)d_in[22];
    const float* b_pbox = (const float*)d_in[23];
    float* out = (float*)d_out;

    char* ws = (char*)d_ws;
    unsigned* bar = (unsigned*)ws;                         // 256B
    unsigned* h2x = (unsigned*)(ws + 256);                 // 2*8192*4 = 65536B
    float* parts  = (float*)(ws + 256 + 65536);            // 64B
    float* base   = (float*)(ws + 256 + 65536 + 64);
    size_t off = 0;
    float* rgb    = base + off; off += (size_t)5921 * 256;
    float* gxg    = base + off; off += (size_t)5730 * 768;
    float* gxc    = base + off; off += (size_t)5730 * 96;
    float* pboxb  = base + off; off += (size_t)5730 * 36;
    float* logitb = base + off; off += 5760;
    float* biasg  = base + off; off += 768;
    float* biasc  = base + off; off += 96;
    unsigned* wpg = (unsigned*)(base + off); off += 98304;   // 24*16*64*4
    unsigned* hdh = (unsigned*)(base + off); off += 9216;    // 2*18*64*4
    unsigned* hdl = (unsigned*)(base + off); off += 9216;
    unsigned* hch = (unsigned*)(base + off); off += 1536;    // 3*2*64*4
    unsigned* hcl = (unsigned*)(base + off); off += 1536;

    (void)hipMemsetAsync(d_ws, 0, 256, stream);            // barrier counter

    prep_bias<<<1, 768, 0, stream>>>(bx_g, bh_g, bx_c, bh_c, biasg, biasc);
    prep_wg<<<384, 256, 0, stream>>>(Wh_g, wpg);
    prep_hd<<<36, 256, 0, stream>>>(W_pbox, W_out, hdh, hdl);
    prep_hcw<<<6, 256, 0, stream>>>(Wh_c, hch, hcl);

    gemm_tiled<false, true><<<dim3(4, 93), 256, 0, stream>>>(flow, W_rgb, b_rgb, rgb, 5921, 256, 4096);
    gemm_tiled<true, false><<<dim3(12, 90), 256, 0, stream>>>(rgb, Wx_g, biasg, gxg, 5730, 768, 512);
    precomp_kernel<<<5730, 256, 0, stream>>>(y, W_bb, b_bb, W_dd, b_dd, W_proj, b_proj,
                                             Wx_c, biasc, W_pbox, b_pbox, W_out, b_out,
                                             gxc, pboxb, logitb);
    seqx<<<NBLK, 512, 0, stream>>>(y, gxg, gxc, pboxb, logitb, wpg, hdh, hdl, hch, hcl,
                                   bh_g, bh_c, h2x, bar, parts);
    reduce_kernel<<<1, 64, 0, stream>>>(parts, out);
}